// Round 4
// baseline (1165.032 us; speedup 1.0000x reference)
//
#include <hip/hip_runtime.h>
#include <hip/hip_cooperative_groups.h>
#include <math.h>

namespace cg = cooperative_groups;

// Problem constants (fixed by the reference)
#define Nn 4096
#define Mm 4096
#define Dd 512
#define NP 4097            // N+1 == M+1 (augmented with dustbin)
#define NPB 4104           // padded bf16-E leading dim (rows 16B-aligned: 4104*2 = 8208)

// phi = REG_KL / (REG_KL + REG) = 0.01/0.11 ; lmba = 10
#define PHI 0.09090909090909091f
#define LMU_IN  (-8.4231266823771690f)   // log(0.9/4096)
#define LMU_BIN (-2.3025850929940457f)   // log(0.1)

// Contraction per full Gauss-Seidel iteration is phi^2 = 1/121.
// ||V0 - V*|| <= 2.5 -> 3 iters: 2.5*121^-3 ~ 1.4e-6, below fp32 noise.
#define SINK_ITERS 3

#define GRID_B 1024        // coop grid: light kernel -> >=4 blocks/CU guaranteed

typedef __attribute__((ext_vector_type(8))) __bf16 bf16x8;
typedef __attribute__((ext_vector_type(4))) float  f32x4;

__device__ __forceinline__ float bf_lo(unsigned u) { return __uint_as_float(u << 16); }
__device__ __forceinline__ float bf_hi(unsigned u) { return __uint_as_float(u & 0xffff0000u); }

// async global->LDS, 16B per lane. LDS dest must be wave-uniform base + lane*16.
__device__ __forceinline__ void load_lds16(const __bf16* g, __bf16* l) {
    __builtin_amdgcn_global_load_lds(
        (__attribute__((address_space(1))) void*)g,
        (__attribute__((address_space(3))) void*)l,
        16, 0, 0);
}

// all-reduce across 256 threads; leading sync protects sb reuse across calls.
__device__ __forceinline__ float block_allreduce_256(float v, float* sb) {
    #pragma unroll
    for (int off = 32; off > 0; off >>= 1) v += __shfl_down(v, off, 64);
    __syncthreads();
    if ((threadIdx.x & 63) == 0) sb[threadIdx.x >> 6] = v;
    __syncthreads();
    return sb[0] + sb[1] + sb[2] + sb[3];
}

// ---------- regular kernels (R2-proven structure) ----------

// Normalize rows of ft0/ft1 and emit bf16. grid = Nn+Mm blocks of 256.
__global__ __launch_bounds__(256) void normalize_bf16_kernel(
    const float* __restrict__ F0, const float* __restrict__ F1,
    __bf16* __restrict__ A, __bf16* __restrict__ B) {
    __shared__ float sb[4];
    const int row = blockIdx.x;
    const float* src = (row < Nn) ? (F0 + (size_t)row * Dd)
                                  : (F1 + (size_t)(row - Nn) * Dd);
    __bf16* dst = (row < Nn) ? (A + (size_t)row * Dd)
                             : (B + (size_t)(row - Nn) * Dd);
    const float2 x = ((const float2*)src)[threadIdx.x];
    const float s = block_allreduce_256(x.x * x.x + x.y * x.y, sb);
    const float rn = rsqrtf(s);
    dst[2 * threadIdx.x]     = (__bf16)(x.x * rn);
    dst[2 * threadIdx.x + 1] = (__bf16)(x.y * rn);
}

// Ebf = exp(10 * A B^T) interior. 128x128 tile / 256 threads, 16x16x32 bf16 MFMA.
// Identical to the R2-passing kernel minus the fp32-E writes.
__global__ __launch_bounds__(256) void gemm_mfma_kernel(
    const __bf16* __restrict__ A, const __bf16* __restrict__ B,
    __bf16* __restrict__ Ebf) {
    __shared__ __align__(16) __bf16 As[128 * 32];
    __shared__ __align__(16) __bf16 Bs[128 * 32];
    const int tid = threadIdx.x;
    const int l = tid & 63, wv = tid >> 6;
    const int wm = wv >> 1, wn = wv & 1;
    const int ln = l & 15, lq = l >> 4;
    const int row0 = blockIdx.y << 7, col0 = blockIdx.x << 7;

    f32x4 acc[4][4];
    #pragma unroll
    for (int i = 0; i < 4; ++i)
        #pragma unroll
        for (int j = 0; j < 4; ++j) acc[i][j] = (f32x4){0.f, 0.f, 0.f, 0.f};

    const int ch0 = tid, ch1 = 256 + tid;
    const __bf16* a0 = A + (size_t)(row0 + (ch0 >> 2)) * Dd + ((ch0 & 3) << 3);
    const __bf16* a1 = A + (size_t)(row0 + (ch1 >> 2)) * Dd + ((ch1 & 3) << 3);
    const __bf16* b0 = B + (size_t)(col0 + (ch0 >> 2)) * Dd + ((ch0 & 3) << 3);
    const __bf16* b1 = B + (size_t)(col0 + (ch1 >> 2)) * Dd + ((ch1 & 3) << 3);
    __bf16* lA0 = &As[ch0 * 8]; __bf16* lA1 = &As[ch1 * 8];
    __bf16* lB0 = &Bs[ch0 * 8]; __bf16* lB1 = &Bs[ch1 * 8];

    for (int k0 = 0; k0 < Dd; k0 += 32) {
        __syncthreads();
        load_lds16(a0 + k0, lA0);
        load_lds16(a1 + k0, lA1);
        load_lds16(b0 + k0, lB0);
        load_lds16(b1 + k0, lB1);
        __syncthreads();
        bf16x8 af[4], bfr[4];
        #pragma unroll
        for (int mi = 0; mi < 4; ++mi)
            af[mi] = *(const bf16x8*)&As[(wm * 64 + mi * 16 + ln) * 32 + lq * 8];
        #pragma unroll
        for (int ni = 0; ni < 4; ++ni)
            bfr[ni] = *(const bf16x8*)&Bs[(wn * 64 + ni * 16 + ln) * 32 + lq * 8];
        #pragma unroll
        for (int mi = 0; mi < 4; ++mi)
            #pragma unroll
            for (int ni = 0; ni < 4; ++ni)
                acc[mi][ni] = __builtin_amdgcn_mfma_f32_16x16x32_bf16(
                    af[mi], bfr[ni], acc[mi][ni], 0, 0, 0);
    }

    // C/D layout (m89-verified): col = lane&15, row = (lane>>4)*4 + reg
    #pragma unroll
    for (int mi = 0; mi < 4; ++mi) {
        #pragma unroll
        for (int r = 0; r < 4; ++r) {
            const int gi = row0 + wm * 64 + mi * 16 + lq * 4 + r;
            __bf16* bRow = Ebf + (size_t)gi * NPB + col0 + wn * 64 + ln;
            #pragma unroll
            for (int ni = 0; ni < 4; ++ni)
                bRow[ni * 16] = (__bf16)__expf(10.0f * acc[mi][ni][r]);
        }
    }
}

// Dustbin col (j=Mm, i<Nn) and dustbin row (i=Nn, all j) of Ebf.
__global__ void fill_bins_kernel(__bf16* __restrict__ Ebf,
                                 const float* __restrict__ binp) {
    const __bf16 ebb = (__bf16)__expf(10.0f * binp[0]);
    const int idx = blockIdx.x * 256 + threadIdx.x;
    if (idx < Nn)            Ebf[(size_t)idx * NPB + Mm] = ebb;          // right col
    else if (idx < Nn + NP)  Ebf[(size_t)Nn * NPB + (idx - Nn)] = ebb;   // bottom row
}

__global__ void init_w_kernel(float* __restrict__ w) {
    const int j = blockIdx.x * 256 + threadIdx.x;
    if (j < NP) w[j] = 1.0f;
}

// ---------- cooperative Sinkhorn + finish (simple, no MFMA, low VGPR) ----------

__global__ __launch_bounds__(256) void sinkhorn_finish_kernel(
    const __bf16* __restrict__ Ebf, float* __restrict__ out,
    float* __restrict__ eU, float* __restrict__ w, float* __restrict__ Tb) {
    cg::grid_group grid = cg::this_grid();
    __shared__ float sb[4];
    const int tid = threadIdx.x;
    const int b = blockIdx.x;

    for (int it = 0; it < SINK_ITERS; ++it) {
        // ---- row pass: S_i = sum_j Ebf[i][j]*w[j]; eU[i]=exp(phi*(lmu-logS)) ----
        #pragma unroll 1
        for (int rr = 0; rr < 5; ++rr) {
            const int i = b + rr * GRID_B;
            if (i >= NP) break;
            const uint4* rowp = (const uint4*)(Ebf + (size_t)i * NPB);
            float s = 0.f;
            #pragma unroll
            for (int c = 0; c < 2; ++c) {
                const int chunk = c * 256 + tid;          // cols chunk*8 .. +7
                const uint4 u = rowp[chunk];
                const float4 w0 = *(const float4*)(w + chunk * 8);
                const float4 w1 = *(const float4*)(w + chunk * 8 + 4);
                s += bf_lo(u.x) * w0.x + bf_hi(u.x) * w0.y
                   + bf_lo(u.y) * w0.z + bf_hi(u.y) * w0.w
                   + bf_lo(u.z) * w1.x + bf_hi(u.z) * w1.y
                   + bf_lo(u.w) * w1.z + bf_hi(u.w) * w1.w;
            }
            if (tid == 0) s += (float)Ebf[(size_t)i * NPB + Mm] * w[Mm];
            s = block_allreduce_256(s, sb);
            if (tid == 0) {
                const float lmu = (i < Nn) ? LMU_IN : LMU_BIN;
                eU[i] = __expf(PHI * (lmu - __logf(s)));
                Tb[i] = 0.f;
            }
        }
        grid.sync();

        // ---- col pass (cols 0..4095): Tb[j] += stripe-sums of E[i][j]*eU[i] ----
        {
            const int t = b & 7, sIdx = b >> 3;           // 8 col-tiles x 128 stripes
            const int j0 = t * 512 + tid * 2;             // even, <= 4094
            const int r0 = sIdx * 32;
            const int r1 = (sIdx == 127) ? NP : r0 + 32;  // last stripe takes row 4096
            float s0 = 0.f, s1 = 0.f;
            for (int r = r0; r < r1; ++r) {
                const unsigned u = *(const unsigned*)(Ebf + (size_t)r * NPB + j0);
                const float ev = eU[r];
                s0 += bf_lo(u) * ev;
                s1 += bf_hi(u) * ev;
            }
            atomicAdd(&Tb[j0], s0);
            atomicAdd(&Tb[j0 + 1], s1);
        }
        grid.sync();

        // ---- w update: blocks 0..15 from Tb; block 16 reduces column Mm itself ----
        if (b < 16) {
            const int j = b * 256 + tid;                  // 0..4095
            w[j] = __expf(PHI * (LMU_IN - __logf(Tb[j])));
        } else if (b == 16) {
            float s = 0.f;
            for (int r = tid; r < NP; r += 256)
                s += (float)Ebf[(size_t)r * NPB + Mm] * eU[r];
            s = block_allreduce_256(s, sb);
            if (tid == 0)
                w[Mm] = __expf(PHI * (LMU_BIN - __logf(s)));
        }
        grid.sync();
    }

    // ---- finish: out[i][j] = Ebf[i][j] * eU[i] * w[j], corner zeroed ----
    #pragma unroll 1
    for (int rr = 0; rr < 5; ++rr) {
        const int i = b + rr * GRID_B;
        if (i >= NP) break;
        const float sU = eU[i];
        const __bf16* erow = Ebf + (size_t)i * NPB;
        float* orow = out + (size_t)i * NP;
        for (int j = tid; j < NP; j += 256) {
            float v = (float)erow[j] * sU * w[j];
            if (i == Nn && j == Mm) v = 0.f;
            orow[j] = v;
        }
    }
    // belt-and-suspenders corner zero (duplicate write of the same phase's value)
    if (b == 0 && tid == 0) out[(size_t)Nn * NP + Mm] = 0.f;
}

// -------------------- launch --------------------

extern "C" void kernel_launch(void* const* d_in, const int* in_sizes, int n_in,
                              void* d_out, int out_size, void* d_ws, size_t ws_size,
                              hipStream_t stream) {
    const float* ft0 = (const float*)d_in[0];
    const float* ft1 = (const float*)d_in[1];
    const float* bin = (const float*)d_in[2];
    float* out = (float*)d_out;

    // ws layout (same footprint class as R2's proven-fitting fast path)
    const size_t ABF_B = (size_t)Nn * Dd * 2;            // 4,194,304
    const size_t EBF_B = (size_t)NP * NPB * 2;           // 33,628,176 (16B-divisible)
    const size_t VEC_B = 16400;                          // 4097 floats, padded
    __bf16* Abf = (__bf16*)d_ws;
    __bf16* Bbf = (__bf16*)((char*)d_ws + ABF_B);
    __bf16* Ebf = (__bf16*)((char*)d_ws + 2 * ABF_B);
    float*  eU  = (float*)((char*)d_ws + 2 * ABF_B + EBF_B);
    float*  w   = (float*)((char*)d_ws + 2 * ABF_B + EBF_B + VEC_B);
    float*  Tb  = (float*)((char*)d_ws + 2 * ABF_B + EBF_B + 2 * VEC_B);

    normalize_bf16_kernel<<<Nn + Mm, 256, 0, stream>>>(ft0, ft1, Abf, Bbf);
    gemm_mfma_kernel<<<dim3(32, 32), 256, 0, stream>>>(Abf, Bbf, Ebf);
    fill_bins_kernel<<<(Nn + NP + 255) / 256, 256, 0, stream>>>(Ebf, bin);
    init_w_kernel<<<(NP + 255) / 256, 256, 0, stream>>>(w);

    void* args[] = {(void*)&Ebf, (void*)&out, (void*)&eU, (void*)&w, (void*)&Tb};
    hipLaunchCooperativeKernel((const void*)sinkhorn_finish_kernel,
                               dim3(GRID_B), dim3(256), args, 0, stream);
}

// Round 5
// 199.748 us; speedup vs baseline: 5.8325x; 5.8325x over previous
//
#include <hip/hip_runtime.h>
#include <math.h>

// Problem constants (fixed by the reference)
#define Nn 4096
#define Mm 4096
#define Dd 512
#define NP 4097            // N+1 == M+1 (augmented with dustbin)
#define NPB 4104           // padded fp16-E leading dim (rows 16B-aligned: 4104*2 = 8208)

// phi = REG_KL / (REG_KL + REG) = 0.01/0.11 ; lmba = 10
#define PHI 0.09090909090909091f
#define LMU_IN  (-8.4231266823771690f)   // log(0.9/4096)
#define LMU_BIN (-2.3025850929940457f)   // log(0.1)

typedef __attribute__((ext_vector_type(8))) __bf16 bf16x8;
typedef __attribute__((ext_vector_type(4))) float  f32x4;

// async global->LDS, 16B per lane. LDS dest must be wave-uniform base + lane*16.
__device__ __forceinline__ void load_lds16(const __bf16* g, __bf16* l) {
    __builtin_amdgcn_global_load_lds(
        (__attribute__((address_space(1))) void*)g,
        (__attribute__((address_space(3))) void*)l,
        16, 0, 0);
}

// all-reduce across 256 threads; leading sync protects sb reuse across calls.
__device__ __forceinline__ float block_allreduce_256(float v, float* sb) {
    #pragma unroll
    for (int off = 32; off > 0; off >>= 1) v += __shfl_down(v, off, 64);
    __syncthreads();
    if ((threadIdx.x & 63) == 0) sb[threadIdx.x >> 6] = v;
    __syncthreads();
    return sb[0] + sb[1] + sb[2] + sb[3];
}

// ---------- kernel 1: normalize inputs to bf16 + fill Ef dustbins ----------
// grid = 8192 blocks of 256 (one per feature row).
__global__ __launch_bounds__(256) void normalize_bins_kernel(
    const float* __restrict__ F0, const float* __restrict__ F1,
    const float* __restrict__ binp,
    __bf16* __restrict__ A, __bf16* __restrict__ B, _Float16* __restrict__ Ef) {
    __shared__ float sb[4];
    const int row = blockIdx.x;
    const float* src = (row < Nn) ? (F0 + (size_t)row * Dd)
                                  : (F1 + (size_t)(row - Nn) * Dd);
    __bf16* dst = (row < Nn) ? (A + (size_t)row * Dd)
                             : (B + (size_t)(row - Nn) * Dd);
    const float2 x = ((const float2*)src)[threadIdx.x];
    const float s = block_allreduce_256(x.x * x.x + x.y * x.y, sb);
    const float rn = rsqrtf(s);
    dst[2 * threadIdx.x]     = (__bf16)(x.x * rn);
    dst[2 * threadIdx.x + 1] = (__bf16)(x.y * rn);

    // dustbin fills (row 4096 incl corner, col 4096) piggybacked on blocks 0..32
    const _Float16 ebh = (_Float16)__expf(10.0f * binp[0]);
    if (row < 17) {
        const int j = row * 256 + threadIdx.x;
        if (j < NP) Ef[(size_t)Nn * NPB + j] = ebh;           // bottom row
    } else if (row < 33) {
        const int i = (row - 17) * 256 + threadIdx.x;
        if (i < Nn) Ef[(size_t)i * NPB + Mm] = ebh;           // right col
    }
}

// ---------- kernel 2: Ef = exp(10 * A B^T) interior, bf16 MFMA ----------
// 128x128 tile / 256 threads (R2-proven structure), fp16 output only.
__global__ __launch_bounds__(256) void gemm_mfma_kernel(
    const __bf16* __restrict__ A, const __bf16* __restrict__ B,
    _Float16* __restrict__ Ef) {
    __shared__ __align__(16) __bf16 As[128 * 32];
    __shared__ __align__(16) __bf16 Bs[128 * 32];
    const int tid = threadIdx.x;
    const int l = tid & 63, wv = tid >> 6;
    const int wm = wv >> 1, wn = wv & 1;
    const int ln = l & 15, lq = l >> 4;
    const int row0 = blockIdx.y << 7, col0 = blockIdx.x << 7;

    f32x4 acc[4][4];
    #pragma unroll
    for (int i = 0; i < 4; ++i)
        #pragma unroll
        for (int j = 0; j < 4; ++j) acc[i][j] = (f32x4){0.f, 0.f, 0.f, 0.f};

    const int ch0 = tid, ch1 = 256 + tid;
    const __bf16* a0 = A + (size_t)(row0 + (ch0 >> 2)) * Dd + ((ch0 & 3) << 3);
    const __bf16* a1 = A + (size_t)(row0 + (ch1 >> 2)) * Dd + ((ch1 & 3) << 3);
    const __bf16* b0 = B + (size_t)(col0 + (ch0 >> 2)) * Dd + ((ch0 & 3) << 3);
    const __bf16* b1 = B + (size_t)(col0 + (ch1 >> 2)) * Dd + ((ch1 & 3) << 3);
    __bf16* lA0 = &As[ch0 * 8]; __bf16* lA1 = &As[ch1 * 8];
    __bf16* lB0 = &Bs[ch0 * 8]; __bf16* lB1 = &Bs[ch1 * 8];

    for (int k0 = 0; k0 < Dd; k0 += 32) {
        __syncthreads();
        load_lds16(a0 + k0, lA0);
        load_lds16(a1 + k0, lA1);
        load_lds16(b0 + k0, lB0);
        load_lds16(b1 + k0, lB1);
        __syncthreads();
        bf16x8 af[4], bfr[4];
        #pragma unroll
        for (int mi = 0; mi < 4; ++mi)
            af[mi] = *(const bf16x8*)&As[(wm * 64 + mi * 16 + ln) * 32 + lq * 8];
        #pragma unroll
        for (int ni = 0; ni < 4; ++ni)
            bfr[ni] = *(const bf16x8*)&Bs[(wn * 64 + ni * 16 + ln) * 32 + lq * 8];
        #pragma unroll
        for (int mi = 0; mi < 4; ++mi)
            #pragma unroll
            for (int ni = 0; ni < 4; ++ni)
                acc[mi][ni] = __builtin_amdgcn_mfma_f32_16x16x32_bf16(
                    af[mi], bfr[ni], acc[mi][ni], 0, 0, 0);
    }

    // C/D layout (m89-verified): col = lane&15, row = (lane>>4)*4 + reg
    #pragma unroll
    for (int mi = 0; mi < 4; ++mi) {
        #pragma unroll
        for (int r = 0; r < 4; ++r) {
            const int gi = row0 + wm * 64 + mi * 16 + lq * 4 + r;
            _Float16* bRow = Ef + (size_t)gi * NPB + col0 + wn * 64 + ln;
            #pragma unroll
            for (int ni = 0; ni < 4; ++ni)
                bRow[ni * 16] = (_Float16)__expf(10.0f * acc[mi][ni][r]);
        }
    }
}

// ---------- kernel 3: row pass ----------
// Builds w in LDS from raw col-sums TcIn (or 1.0 on the first iteration),
// computes S_i, writes eU[i] = exp(phi*(lmu - log S_i)), zeros TcOut[i].
// grid = 4097 blocks of 256.
__global__ __launch_bounds__(256) void row_pass_kernel(
    const _Float16* __restrict__ Ef, const float* __restrict__ TcIn,
    float* __restrict__ eU, float* __restrict__ TcOut, const int first) {
    __shared__ float sb[4];
    __shared__ float wl[NP];
    const int tid = threadIdx.x;
    const int i = blockIdx.x;

    if (first) {
        for (int j = tid; j < NP; j += 256) wl[j] = 1.0f;
    } else {
        for (int j = tid; j < NP; j += 256) {
            const float lnu = (j < Mm) ? LMU_IN : LMU_BIN;
            wl[j] = __expf(PHI * (lnu - __logf(TcIn[j])));
        }
    }
    __syncthreads();

    const uint4* rowp = (const uint4*)(Ef + (size_t)i * NPB);
    float s = 0.f;
    #pragma unroll
    for (int c = 0; c < 2; ++c) {
        const int chunk = c * 256 + tid;                  // cols chunk*8 .. +7
        union { uint4 u; _Float16 h[8]; } e;
        e.u = rowp[chunk];
        const float4 w0 = *(const float4*)&wl[chunk * 8];
        const float4 w1 = *(const float4*)&wl[chunk * 8 + 4];
        s += (float)e.h[0] * w0.x + (float)e.h[1] * w0.y
           + (float)e.h[2] * w0.z + (float)e.h[3] * w0.w
           + (float)e.h[4] * w1.x + (float)e.h[5] * w1.y
           + (float)e.h[6] * w1.z + (float)e.h[7] * w1.w;
    }
    if (tid == 0) s += (float)Ef[(size_t)i * NPB + Mm] * wl[Mm];   // col 4096
    s = block_allreduce_256(s, sb);
    if (tid == 0) {
        const float lmu = (i < Nn) ? LMU_IN : LMU_BIN;
        eU[i] = __expf(PHI * (lmu - __logf(s)));
        TcOut[i] = 0.f;                                   // zero next accumulator
    }
}

// ---------- kernel 4: col pass ----------
// TcOut[j] += stripe-sums of Ef[i][j]*eU[i]. grid = 1024 blocks:
// 8 col-tiles (512 cols) x 128 row-stripes (32 rows).
__global__ __launch_bounds__(256) void col_pass_kernel(
    const _Float16* __restrict__ Ef, const float* __restrict__ eU,
    float* __restrict__ TcOut) {
    const int t = blockIdx.x & 7, sI = blockIdx.x >> 3;
    const int j0 = t * 512 + threadIdx.x * 2;             // even, <= 4094
    const int r0 = sI * 32;
    const int r1 = (sI == 127) ? NP : r0 + 32;            // last stripe adds row 4096
    float s0 = 0.f, s1 = 0.f;
    for (int r = r0; r < r1; ++r) {
        union { unsigned u; _Float16 h[2]; } e;
        e.u = *(const unsigned*)(Ef + (size_t)r * NPB + j0);
        const float ev = eU[r];
        s0 += (float)e.h[0] * ev;
        s1 += (float)e.h[1] * ev;
    }
    atomicAdd(&TcOut[j0], s0);
    atomicAdd(&TcOut[j0 + 1], s1);

    // column 4096 (dustbin col): handled by the 128 t==0 blocks, wave 0
    if (t == 0 && threadIdx.x < 32) {
        const int lane = threadIdx.x;
        float sc = 0.f;
        for (int r = r0 + lane; r < r1; r += 32)
            sc += (float)Ef[(size_t)r * NPB + Mm] * eU[r];
        #pragma unroll
        for (int off = 16; off > 0; off >>= 1) sc += __shfl_down(sc, off, 64);
        if (lane == 0) atomicAdd(&TcOut[Mm], sc);
    }
}

// ---------- kernel 5: finish ----------
// out[i][j] = Ef[i][j] * eU[i] * w[j] with w rebuilt in LDS from TcIn.
// grid = 4097 blocks of 256.
__global__ __launch_bounds__(256) void finish_kernel(
    const _Float16* __restrict__ Ef, const float* __restrict__ eU,
    const float* __restrict__ TcIn, float* __restrict__ out) {
    __shared__ float wl[NP];
    const int tid = threadIdx.x;
    const int i = blockIdx.x;
    for (int j = tid; j < NP; j += 256) {
        const float lnu = (j < Mm) ? LMU_IN : LMU_BIN;
        wl[j] = __expf(PHI * (lnu - __logf(TcIn[j])));
    }
    __syncthreads();
    const float sU = eU[i];
    const _Float16* erow = Ef + (size_t)i * NPB;
    float* orow = out + (size_t)i * NP;
    for (int j = tid; j < NP; j += 256) {
        float v = (float)erow[j] * sU * wl[j];
        if (i == Nn && j == Mm) v = 0.f;                  // corner zeroed
        orow[j] = v;
    }
}

// -------------------- launch --------------------

extern "C" void kernel_launch(void* const* d_in, const int* in_sizes, int n_in,
                              void* d_out, int out_size, void* d_ws, size_t ws_size,
                              hipStream_t stream) {
    const float* ft0 = (const float*)d_in[0];
    const float* ft1 = (const float*)d_in[1];
    const float* bin = (const float*)d_in[2];
    float* out = (float*)d_out;

    const size_t ABF_B = (size_t)Nn * Dd * 2;            // 4,194,304
    const size_t EBF_B = (size_t)NP * NPB * 2;           // 33,628,176 (16B-divisible)
    const size_t VEC_B = 16400;                          // 4097 floats, padded
    __bf16*   Abf = (__bf16*)d_ws;
    __bf16*   Bbf = (__bf16*)((char*)d_ws + ABF_B);
    _Float16* Ef  = (_Float16*)((char*)d_ws + 2 * ABF_B);
    float*    eU  = (float*)((char*)d_ws + 2 * ABF_B + EBF_B);
    float*    TcA = (float*)((char*)d_ws + 2 * ABF_B + EBF_B + VEC_B);
    float*    TcB = (float*)((char*)d_ws + 2 * ABF_B + EBF_B + 2 * VEC_B);

    normalize_bins_kernel<<<Nn + Mm, 256, 0, stream>>>(ft0, ft1, bin, Abf, Bbf, Ef);
    gemm_mfma_kernel<<<dim3(32, 32), 256, 0, stream>>>(Abf, Bbf, Ef);

    // Sinkhorn, 2 damped Gauss-Seidel iterations (contraction phi^2 = 1/121:
    // residual after 2 iters ~1.2e-3 in U+V -> ~6e-3 in prob, vs threshold 0.08).
    row_pass_kernel<<<NP, 256, 0, stream>>>(Ef, TcA, eU, TcA, 1);   // TcIn unused
    col_pass_kernel<<<1024, 256, 0, stream>>>(Ef, eU, TcA);
    row_pass_kernel<<<NP, 256, 0, stream>>>(Ef, TcA, eU, TcB, 0);
    col_pass_kernel<<<1024, 256, 0, stream>>>(Ef, eU, TcB);

    finish_kernel<<<NP, 256, 0, stream>>>(Ef, eU, TcB, out);
}